// Round 5
// baseline (294.811 us; speedup 1.0000x reference)
//
#include <hip/hip_runtime.h>
#include <math.h>

// One wave (64 threads) per block; each wave owns 256 cells (4/thread, strided 64).
//  L0: 16224 cells -> 64 blocks (g=13, anchors 6,7,8; last block nv=96)
//  L1: 64896 cells -> 254 blocks (g=26, anchors 3,4,5; last block nv=128)
//  L2: 259584 cells -> 1014 blocks (g=52, anchors 0,1,2; exact)
#define NB0 64
#define NB1 254
#define NB2 1014
#define NBLOCKS (NB0 + NB1 + NB2)

// 4-byte-aligned float4 (target loads: 20B stride, L1-resident broadcast)
typedef float f4a __attribute__((ext_vector_type(4), aligned(4)));

// anchors ordered [layer][a]: layer0 = ANCHORS[6,7,8], layer1 = [3,4,5], layer2 = [0,1,2]
__constant__ float c_anch[9][2] = {
    {116.f, 90.f}, {156.f, 198.f}, {373.f, 326.f},
    { 30.f, 61.f}, { 62.f,  45.f}, { 59.f, 119.f},
    { 10.f, 13.f}, { 16.f,  30.f}, { 33.f,  23.f}
};

// stable softplus: log(1+exp(x)) = max(x,0) + log(1+exp(-|x|))
__device__ __forceinline__ float softplusf(float x) {
    float ax = fabsf(x);
    return fmaxf(x, 0.f) + __logf(1.f + __expf(-ax));
}

__device__ __forceinline__ float sigmoidf(float x) {
    return __fdividef(1.f, 1.f + __expf(-x));
}

// ---- per-wave task: 256 cells, wave-private LDS staging, no barriers ----
// Stage f-mapping (class chunks of 8 ch): f = k*64+lane -> cell=f>>3, ch=f&7:
// one instr = 8 cells x 32B contiguous runs (coalesced); LDS stride 9 (odd)
// makes consume reads S9[(lane+64r)*9+c] conflict-free (2-way = free).
template<int G, int LAYER>
__device__ __forceinline__ float wave_task(
    const float* __restrict__ pred, const float* __restrict__ tru,
    const float* __restrict__ tgt, int task, int cells, int lane,
    float* __restrict__ S5, float* __restrict__ S9)
{
    constexpr int HW = G * G;
    constexpr int CPB = 3 * HW;               // cells per batch image
    const int cell0 = task * 256;
    const int nv = cells - cell0;             // 96, 128, or 256
    const int nvc = min(nv, 256);
    const float* tw = tru + (size_t)cell0 * 85;

    // per-r (4 cells/thread) index decomposition — all divisors constexpr
    float gate[4], gxv[4], gyv[4], awv[4], ahv[4];
    int pbo[4], bb[4];
#pragma unroll
    for (int r = 0; r < 4; r++) {
        int li = lane + 64 * r;
        gate[r] = (li < nv) ? 1.f : 0.f;
        int c = cell0 + li;
        if (c > cells - 1) c = cells - 1;     // clamp: inactive lanes only
        int b = c / CPB;
        int rem = c - b * CPB;
        int a = rem / HW;
        int ij = rem - a * HW;
        int i = ij / G;
        int j = ij - i * G;
        bb[r]  = b;
        pbo[r] = ((b * 3 + a) * 85) * HW + ij;
        gxv[r] = (float)j;
        gyv[r] = (float)i;
        awv[r] = c_anch[LAYER * 3 + a][0];
        ahv[r] = c_anch[LAYER * 3 + a][1];
    }

    // ---- stage head (ch 0..4 of 256 cells; f = cell*5+ch is LINEAR in LDS) ----
    float hreg[20];
#pragma unroll
    for (int k = 0; k < 20; k++) {
        int f = k * 64 + lane;
        int cell = f / 5;
        int ch = f - cell * 5;
        int cc = min(cell, nvc - 1);
        hreg[k] = tw[cc * 85 + ch];
    }
    // ---- stage class chunk 0 (ch 5..12) — stays in flight under head consume ----
    float creg[32];
#pragma unroll
    for (int k = 0; k < 32; k++) {
        int f = k * 64 + lane;
        int cell = f >> 3;
        int cc = min(cell, nvc - 1);
        creg[k] = tw[cc * 85 + 5 + (f & 7)];
    }
    // write head (vmcnt wait covers hreg only; creg loads younger, stay out)
#pragma unroll
    for (int k = 0; k < 20; k++)
        S5[k * 64 + lane] = hreg[k];

    float acc = 0.f;
    float maskg[4];

    // ---- head consume: xy/wh/conf/IoU for this thread's 4 cells ----
    // big VALU stretch (4x20 IoU iters) = latency cover for chunk-0 loads
#pragma unroll
    for (int r = 0; r < 4; r++) {
        int row = lane + 64 * r;
        float y0 = S5[row * 5 + 0];
        float y1 = S5[row * 5 + 1];
        float y2 = S5[row * 5 + 2];
        float y3 = S5[row * 5 + 3];
        float mk = S5[row * 5 + 4];
        maskg[r] = gate[r] * mk;

        const float* pb = pred + (size_t)pbo[r];
        float r0 = pb[0];
        float r1 = pb[HW];
        float r2 = pb[2 * HW];
        float r3 = pb[3 * HW];
        float r4 = pb[4 * HW];

        float gf = (float)G, gx = gxv[r], gy = gyv[r];
        float aw = awv[r], ah = ahv[r];

        float tmp = 0.f;
        // xy loss: bce(sigmoid(r), t) = softplus(r) - t*r
        float true_x = y0 * gf - gx;
        float true_y = y1 * gf - gy;
        float ls = 2.f - y2 * y3;
        float lxy = (softplusf(r0) - true_x * r0) + (softplusf(r1) - true_y * r1);
        tmp += mk * ls * lxy;

        // wh loss
        float twl = __logf(y2 * (416.f / aw));
        float thl = __logf(y3 * (416.f / ah));
        float dw = r2 - twl, dh = r3 - thl;
        tmp += mk * ls * 0.5f * (dw * dw + dh * dh);

        // conf bce
        float cbce = softplusf(r4) - mk * r4;

        // IoU vs 20 targets -> neg mask
        float sx = sigmoidf(r0);
        float sy = sigmoidf(r1);
        float bx = __fdividef(sx + gx, gf);
        float by = __fdividef(sy + gy, gf);
        float bw = __expf(r2) * aw * (1.f / 416.f);
        float bh = __expf(r3) * ah * (1.f / 416.f);
        float a1 = bw * bh;
        float b1minx = bx - 0.5f * bw, b1maxx = bx + 0.5f * bw;
        float b1miny = by - 0.5f * bh, b1maxy = by + 0.5f * bh;

        const float* tg = tgt + bb[r] * 100;
        float best = 0.f;
#pragma unroll 5
        for (int k = 0; k < 20; k++) {
            f4a t = *reinterpret_cast<const f4a*>(tg + k * 5);  // tx,ty,tw,th
            float hw2 = 0.5f * t.z, hh2 = 0.5f * t.w;
            float iw = fminf(b1maxx, t.x + hw2) - fmaxf(b1minx, t.x - hw2);
            float ih = fminf(b1maxy, t.y + hh2) - fmaxf(b1miny, t.y - hh2);
            iw = fmaxf(iw, 0.f);
            ih = fmaxf(ih, 0.f);
            float inter = iw * ih;
            float iou = __fdividef(inter, a1 + t.z * t.w - inter);
            best = fmaxf(best, iou);
        }
        float neg = (best < 0.5f) ? 1.f : 0.f;
        tmp += mk * cbce + (1.f - mk) * neg * cbce;

        acc += gate[r] * tmp;
    }

    // ---- class loop: 10 chunks of 8 channels, write q / stage q+1 / consume q ----
    float cls[4] = {0.f, 0.f, 0.f, 0.f};
    for (int q = 0; q < 10; q++) {
        // write chunk q to LDS (waits for creg loads issued one phase ago)
#pragma unroll
        for (int k = 0; k < 32; k++) {
            int f = k * 64 + lane;
            S9[(f >> 3) * 9 + (f & 7)] = creg[k];
        }
        // stage chunk q+1 (in flight under consume q)
        if (q < 9) {
#pragma unroll
            for (int k = 0; k < 32; k++) {
                int f = k * 64 + lane;
                int cell = f >> 3;
                int cc = min(cell, nvc - 1);
                creg[k] = tw[cc * 85 + 5 + 8 * (q + 1) + (f & 7)];
            }
        }
        // consume chunk q: pred loads are 4 back-to-back 256B wave-loads per
        // channel = 1KB contiguous bursts (the DRAM-granularity fix)
        int chbase = 5 + 8 * q;
#pragma unroll
        for (int r = 0; r < 4; r++) {
            int row = lane + 64 * r;
            const float* pb = pred + (size_t)pbo[r] + (size_t)chbase * HW;
            float c8 = 0.f;
#pragma unroll
            for (int c = 0; c < 8; c++) {
                float x = pb[(size_t)c * HW];
                float t = S9[row * 9 + c];
                c8 += softplusf(x) - t * x;
            }
            cls[r] += c8;
        }
    }
#pragma unroll
    for (int r = 0; r < 4; r++)
        acc += maskg[r] * cls[r];

    return acc;
}

__global__ __launch_bounds__(64, 2) void yolo_loss_main(
    const float* __restrict__ p0, const float* __restrict__ p1, const float* __restrict__ p2,
    const float* __restrict__ t0, const float* __restrict__ t1, const float* __restrict__ t2,
    const float* __restrict__ tgt, float* __restrict__ partials)
{
    __shared__ float S5[256 * 5];   // head staging (linear)
    __shared__ float S9[256 * 9];   // class-chunk staging (stride 9)

    int blk = blockIdx.x;
    int lane = threadIdx.x;
    float acc;
    if (blk < NB0)
        acc = wave_task<13, 0>(p0, t0, tgt, blk, 16224, lane, S5, S9);
    else if (blk < NB0 + NB1)
        acc = wave_task<26, 1>(p1, t1, tgt, blk - NB0, 64896, lane, S5, S9);
    else
        acc = wave_task<52, 2>(p2, t2, tgt, blk - NB0 - NB1, 259584, lane, S5, S9);

    // single-wave block: shuffle reduction, lane 0 stores
    for (int off = 32; off > 0; off >>= 1)
        acc += __shfl_down(acc, off, 64);
    if (lane == 0)
        partials[blk] = acc;
}

__global__ __launch_bounds__(256) void yolo_loss_reduce(
    const float* __restrict__ partials, float* __restrict__ out)
{
    float s = 0.f;
    for (int i = threadIdx.x; i < NBLOCKS; i += 256)
        s += partials[i];
    for (int off = 32; off > 0; off >>= 1)
        s += __shfl_down(s, off, 64);
    __shared__ float sh[256 / 64];
    if ((threadIdx.x & 63) == 0)
        sh[threadIdx.x >> 6] = s;
    __syncthreads();
    if (threadIdx.x == 0) {
        float tot = 0.f;
        for (int wv = 0; wv < 256 / 64; wv++) tot += sh[wv];
        out[0] = tot;
    }
}

extern "C" void kernel_launch(void* const* d_in, const int* in_sizes, int n_in,
                              void* d_out, int out_size, void* d_ws, size_t ws_size,
                              hipStream_t stream) {
    // setup_inputs() dict order is INTERLEAVED:
    //   d_in[0]=y_pred0, d_in[1]=y_true0, d_in[2]=y_pred1, d_in[3]=y_true1,
    //   d_in[4]=y_pred2, d_in[5]=y_true2, d_in[6]=target
    const float* p0  = (const float*)d_in[0];
    const float* t0  = (const float*)d_in[1];
    const float* p1  = (const float*)d_in[2];
    const float* t1  = (const float*)d_in[3];
    const float* p2  = (const float*)d_in[4];
    const float* t2  = (const float*)d_in[5];
    const float* tgt = (const float*)d_in[6];
    float* partials  = (float*)d_ws;   // NBLOCKS floats; every slot written each call

    yolo_loss_main<<<NBLOCKS, 64, 0, stream>>>(p0, p1, p2, t0, t1, t2, tgt, partials);
    yolo_loss_reduce<<<1, 256, 0, stream>>>(partials, (float*)d_out);
}

// Round 6
// 250.282 us; speedup vs baseline: 1.1779x; 1.1779x over previous
//
#include <hip/hip_runtime.h>
#include <math.h>

#define BLOCK 256
// Layer cell counts (b=32, 3 anchors):
//  L0: 32*3*13*13 = 16224  -> 64 blocks   (13x13, anchors 6,7,8)
//  L1: 32*3*26*26 = 64896  -> 254 blocks  (26x26, anchors 3,4,5)
//  L2: 32*3*52*52 = 259584 -> 1014 blocks (52x52, anchors 0,1,2)
#define NB0 64
#define NB1 254
#define NB2 1014
#define NBLOCKS (NB0 + NB1 + NB2)

// 4-byte-aligned float4 (only for target loads: 20B stride, L1-resident broadcast)
typedef float f4a __attribute__((ext_vector_type(4), aligned(4)));

// anchors ordered [layer][a]: layer0 = ANCHORS[6,7,8], layer1 = [3,4,5], layer2 = [0,1,2]
__constant__ float c_anch[9][2] = {
    {116.f, 90.f}, {156.f, 198.f}, {373.f, 326.f},
    { 30.f, 61.f}, { 62.f,  45.f}, { 59.f, 119.f},
    { 10.f, 13.f}, { 16.f,  30.f}, { 33.f,  23.f}
};

// stable softplus: log(1+exp(x)) = max(x,0) + log(1+exp(-|x|))
__device__ __forceinline__ float softplusf(float x) {
    float ax = fabsf(x);
    return fmaxf(x, 0.f) + __logf(1.f + __expf(-ax));
}

__device__ __forceinline__ float sigmoidf(float x) {
    return __fdividef(1.f, 1.f + __expf(-x));
}

// ---- wave-private y_true staging (NO __syncthreads: a wave's ds_writes are
// visible to itself via the in-order DS pipe + compiler lgkmcnt waits). ----
// Class chunk Q = y_true channels [5+16Q, 5+16Q+16) for this wave's 64 cells.
// Stage mapping: instr k, lane l -> cell = k*4 + (l>>4), ch = l&15:
// 64 lanes cover 4 x 64B contiguous runs (stride 340B) — coalesced.

template<int Q>
__device__ __forceinline__ void stage_cls(const float* __restrict__ tw, int lane,
                                          int nvc, bool full, float* r) {
    if (full) {
        int lo = (lane >> 4) * 85 + (lane & 15);
#pragma unroll
        for (int k = 0; k < 16; k++)
            r[k] = tw[lo + k * 340 + 5 + Q * 16];
    } else {
        // exactly one wave in the whole grid takes this path (L0 blk63 wv1)
#pragma unroll
        for (int k = 0; k < 16; k++) {
            int cc = min(k * 4 + (lane >> 4), nvc - 1);
            r[k] = tw[cc * 85 + (lane & 15) + 5 + Q * 16];
        }
    }
}

__device__ __forceinline__ void write_cls(float (*S)[17], int lane, const float* r) {
#pragma unroll
    for (int k = 0; k < 16; k++)
        S[k * 4 + (lane >> 4)][lane & 15] = r[k];
}

// One class phase (MLP-batched):
//   1. batch-issue 16 pred loads for chunk Q into x[16]   (16 outstanding vmem)
//   2. sched_barrier: nothing crosses — loads stay issued FIRST
//   3. ds_write chunk-Q y_true (vmcnt wait for creg leaves pred batch in flight)
//   4. issue chunk-(Q+1) y_true loads                      (overlap pred wait)
//   5. sched_barrier, then compute (vmcnt wait for pred leaves trues in flight)
template<int Q>
__device__ __forceinline__ void class_phase(const float* __restrict__ tw,
                                            const float* __restrict__ pb,
                                            float (*S)[17], int lane, int nvc,
                                            bool full, int hw, float* creg,
                                            float& cls, bool active) {
    float x[16];
    if (active) {
#pragma unroll
        for (int c = 0; c < 16; c++)
            x[c] = pb[(size_t)((5 + Q * 16 + c) * hw)];   // lane-coalesced 256B
    }
    __builtin_amdgcn_sched_barrier(0);
    write_cls(S, lane, creg);
    if constexpr (Q < 4)
        stage_cls<Q + 1>(tw, lane, nvc, full, creg);
    __builtin_amdgcn_sched_barrier(0);
    if (active) {
#pragma unroll
        for (int c = 0; c < 16; c++) {
            float t = S[lane][c];          // stride-17: 2-way bank alias = free
            cls += softplusf(x[c]) - t * x[c];
        }
    }
}

// __launch_bounds__(256,4): VGPR cap 128 — room for x[16]+creg[16] batching
// without spill. 4 waves/SIMD = 16 waves/CU, which is what R4 measured anyway.
__global__ __launch_bounds__(BLOCK, 4) void yolo_loss_main(
    const float* __restrict__ p0, const float* __restrict__ p1, const float* __restrict__ p2,
    const float* __restrict__ t0, const float* __restrict__ t1, const float* __restrict__ t2,
    const float* __restrict__ tgt, float* __restrict__ partials)
{
    // per-wave private tiles -> no cross-wave coordination, no barriers
    __shared__ float sh[4][64][17];   // 17408 B

    int blk = blockIdx.x;
    const float* pred;
    const float* tru;
    int layer, g, cells, bbase;
    if (blk < NB0)            { layer = 0; pred = p0; tru = t0; g = 13; cells = 16224;  bbase = 0; }
    else if (blk < NB0 + NB1) { layer = 1; pred = p1; tru = t1; g = 26; cells = 64896;  bbase = NB0; }
    else                      { layer = 2; pred = p2; tru = t2; g = 52; cells = 259584; bbase = NB0 + NB1; }

    int tid = threadIdx.x;
    int lane = tid & 63;
    int wv = tid >> 6;
    int cell0 = (blk - bbase) * BLOCK + wv * 64;   // this wave's first cell
    int nv = cells - cell0;                        // valid cells for this wave
    float acc = 0.f;

    if (nv > 0) {                                  // wave-uniform branch
        float (*S)[17] = sh[wv];
        bool full = (nv >= 64);
        int nvc = full ? 64 : nv;
        bool active = lane < nv;
        const float* tw = tru + (size_t)cell0 * 85;

        int cidx = active ? (cell0 + lane) : (cells - 1);
        int hw = g * g;
        int ij = cidx % hw;
        int a  = (cidx / hw) % 3;
        int b  = cidx / (3 * hw);
        int i  = ij / g;
        int j  = ij - i * g;
        // raw[b][a][i][j][c] = y_pred[b][a*85+c][i][j] (channel stride hw, coalesced)
        const float* pb = pred + (size_t)((b * 3 + a) * 85) * hw + ij;

        // ---- stage head: ch 0..4 x 64 cells, flat f = cell*5+ch mapping ----
        {
            float hreg[5];
#pragma unroll
            for (int k = 0; k < 5; k++) {
                int f = k * 64 + lane;
                int cell = f / 5;
                int ch = f - cell * 5;
                int cc = full ? cell : min(cell, nvc - 1);
                hreg[k] = tw[cc * 85 + ch];
            }
#pragma unroll
            for (int k = 0; k < 5; k++) {
                int f = k * 64 + lane;
                int cell = f / 5;
                int ch = f - cell * 5;
                S[cell][ch] = hreg[k];
            }
        }

        float creg[16];
        stage_cls<0>(tw, lane, nvc, full, creg);   // chunk0 latency hides under head

        float cls = 0.f, mask = 0.f;
        if (active) {
            float y0 = S[lane][0], y1 = S[lane][1], y2 = S[lane][2], y3 = S[lane][3];
            mask = S[lane][4];

            float r0 = pb[0];
            float r1 = pb[hw];
            float r2 = pb[2 * hw];
            float r3 = pb[3 * hw];
            float r4 = pb[4 * hw];

            float gf = (float)g, gx = (float)j, gy = (float)i;
            float aw = c_anch[layer * 3 + a][0];
            float ah = c_anch[layer * 3 + a][1];

            // xy loss: bce(sigmoid(r), t) = softplus(r) - t*r
            float true_x = y0 * gf - gx;
            float true_y = y1 * gf - gy;
            float ls = 2.f - y2 * y3;   // loss_scale
            float lxy = (softplusf(r0) - true_x * r0) + (softplusf(r1) - true_y * r1);
            acc += mask * ls * lxy;

            // wh loss
            float tw_ = __logf(y2 * (416.f / aw));
            float th_ = __logf(y3 * (416.f / ah));
            float dw = r2 - tw_, dh = r3 - th_;
            acc += mask * ls * 0.5f * (dw * dw + dh * dh);

            // conf bce
            float cbce = softplusf(r4) - mask * r4;

            // IoU vs 20 targets -> neg mask
            float sx = sigmoidf(r0);
            float sy = sigmoidf(r1);
            float bx = __fdividef(sx + gx, gf);
            float by = __fdividef(sy + gy, gf);
            float bw = __expf(r2) * aw * (1.f / 416.f);
            float bh = __expf(r3) * ah * (1.f / 416.f);
            float a1 = bw * bh;
            float b1minx = bx - 0.5f * bw, b1maxx = bx + 0.5f * bw;
            float b1miny = by - 0.5f * bh, b1maxy = by + 0.5f * bh;

            const float* tg = tgt + b * 20 * 5;
            float best = 0.f;
#pragma unroll 5
            for (int k = 0; k < 20; k++) {
                f4a t = *reinterpret_cast<const f4a*>(tg + k * 5);  // tx,ty,tw,th
                float hw2 = 0.5f * t.z, hh2 = 0.5f * t.w;
                float iw = fminf(b1maxx, t.x + hw2) - fmaxf(b1minx, t.x - hw2);
                float ih = fminf(b1maxy, t.y + hh2) - fmaxf(b1miny, t.y - hh2);
                iw = fmaxf(iw, 0.f);
                ih = fmaxf(ih, 0.f);
                float inter = iw * ih;
                float iou = __fdividef(inter, a1 + t.z * t.w - inter);
                best = fmaxf(best, iou);
            }
            float neg = (best < 0.5f) ? 1.f : 0.f;
            acc += mask * cbce + (1.f - mask) * neg * cbce;
        }

        // ---- class chunks: batched pred loads, overlapped staging ----
        class_phase<0>(tw, pb, S, lane, nvc, full, hw, creg, cls, active);
        class_phase<1>(tw, pb, S, lane, nvc, full, hw, creg, cls, active);
        class_phase<2>(tw, pb, S, lane, nvc, full, hw, creg, cls, active);
        class_phase<3>(tw, pb, S, lane, nvc, full, hw, creg, cls, active);
        class_phase<4>(tw, pb, S, lane, nvc, full, hw, creg, cls, active);

        if (active) acc += mask * cls;
    }

    // ---- block reduction: wave shuffle then LDS (only barrier in the kernel) ----
    for (int off = 32; off > 0; off >>= 1)
        acc += __shfl_down(acc, off, 64);
    __shared__ float shr[BLOCK / 64];
    if ((threadIdx.x & 63) == 0)
        shr[threadIdx.x >> 6] = acc;
    __syncthreads();
    if (threadIdx.x == 0) {
        float s = 0.f;
        for (int w = 0; w < BLOCK / 64; w++) s += shr[w];
        partials[blockIdx.x] = s;
    }
}

__global__ __launch_bounds__(BLOCK) void yolo_loss_reduce(
    const float* __restrict__ partials, float* __restrict__ out)
{
    float s = 0.f;
    for (int i = threadIdx.x; i < NBLOCKS; i += BLOCK)
        s += partials[i];
    for (int off = 32; off > 0; off >>= 1)
        s += __shfl_down(s, off, 64);
    __shared__ float sh[BLOCK / 64];
    if ((threadIdx.x & 63) == 0)
        sh[threadIdx.x >> 6] = s;
    __syncthreads();
    if (threadIdx.x == 0) {
        float tot = 0.f;
        for (int wv = 0; wv < BLOCK / 64; wv++) tot += sh[wv];
        out[0] = tot;
    }
}

extern "C" void kernel_launch(void* const* d_in, const int* in_sizes, int n_in,
                              void* d_out, int out_size, void* d_ws, size_t ws_size,
                              hipStream_t stream) {
    // setup_inputs() dict order is INTERLEAVED:
    //   d_in[0]=y_pred0, d_in[1]=y_true0, d_in[2]=y_pred1, d_in[3]=y_true1,
    //   d_in[4]=y_pred2, d_in[5]=y_true2, d_in[6]=target
    const float* p0  = (const float*)d_in[0];
    const float* t0  = (const float*)d_in[1];
    const float* p1  = (const float*)d_in[2];
    const float* t1  = (const float*)d_in[3];
    const float* p2  = (const float*)d_in[4];
    const float* t2  = (const float*)d_in[5];
    const float* tgt = (const float*)d_in[6];
    float* partials  = (float*)d_ws;   // NBLOCKS floats; every slot written each call

    yolo_loss_main<<<NBLOCKS, BLOCK, 0, stream>>>(p0, p1, p2, t0, t1, t2, tgt, partials);
    yolo_loss_reduce<<<1, BLOCK, 0, stream>>>(partials, (float*)d_out);
}